// Round 10
// baseline (126.856 us; speedup 1.0000x reference)
//
#include <hip/hip_runtime.h>
#include <cstdint>

#define T_SEQ 4096
#define E_DIM 1024
#define N_B   8
#define SC    128      // seq positions per block
#define TILE_P 148     // s0-10 .. s0+137 (37 groups of 4 rows)
typedef float v2f __attribute__((ext_vector_type(2)));

constexpr int LW[4] = {2, 8, 12, 6};

// dec_lo
constexpr float DLf[4][12] = {
  {0.7071067811865476f, 0.7071067811865476f, 0,0,0,0,0,0,0,0,0,0},
  {-0.010597401784997278f, 0.032883011666982945f, 0.030841381835986965f, -0.18703481171888114f,
   -0.02798376941698385f, 0.6308807679295904f, 0.7148465705525415f, 0.23037781330885523f, 0,0,0,0},
  {-0.007800708325034148f, 0.0017677118642428036f, 0.04472490177066578f, -0.021060292512300564f,
   -0.07263752278646252f, 0.3379294217276218f, 0.787641141030194f, 0.4910559419267466f,
   -0.048311742585633f, -0.11799011114819057f, 0.0034907120842174702f, 0.015404109327027373f},
  {-0.08838834764831845f, 0.08838834764831845f, 0.7071067811865476f, 0.7071067811865476f,
    0.08838834764831845f, -0.08838834764831845f, 0,0,0,0,0,0},
};
// dec_hi
constexpr float DHf[4][12] = {
  {-0.7071067811865476f, 0.7071067811865476f, 0,0,0,0,0,0,0,0,0,0},
  {-0.23037781330885523f, 0.7148465705525415f, -0.6308807679295904f, -0.02798376941698385f,
    0.18703481171888114f, 0.030841381835986965f, -0.032883011666982945f, -0.010597401784997278f, 0,0,0,0},
  {-0.015404109327027373f, 0.0034907120842174702f, 0.11799011114819057f, -0.048311742585633f,
   -0.4910559419267466f, 0.787641141030194f, -0.3379294217276218f, -0.07263752278646252f,
    0.021060292512300564f, 0.04472490177066578f, -0.0017677118642428036f, -0.007800708325034148f},
  {0,0,-0.7071067811865476f, 0.7071067811865476f, 0,0, 0,0,0,0,0,0},
};
// rec_lo
constexpr float RLf[4][12] = {
  {0.7071067811865476f, 0.7071067811865476f, 0,0,0,0,0,0,0,0,0,0},
  {0.23037781330885523f, 0.7148465705525415f, 0.6308807679295904f, -0.02798376941698385f,
   -0.18703481171888114f, 0.030841381835986965f, 0.032883011666982945f, -0.010597401784997278f, 0,0,0,0},
  {0.015404109327027373f, 0.0034907120842174702f, -0.11799011114819057f, -0.048311742585633f,
   0.4910559419267466f, 0.787641141030194f, 0.3379294217276218f, -0.07263752278646252f,
   -0.021060292512300564f, 0.04472490177066578f, 0.0017677118642428036f, -0.007800708325034148f},
  {0,0,0.7071067811865476f, 0.7071067811865476f, 0,0, 0,0,0,0,0,0},
};
// rec_hi
constexpr float RHf[4][12] = {
  {0.7071067811865476f, -0.7071067811865476f, 0,0,0,0,0,0,0,0,0,0},
  {-0.010597401784997278f, -0.032883011666982945f, 0.030841381835986965f, 0.18703481171888114f,
   -0.02798376941698385f, -0.6308807679295904f, 0.7148465705525415f, -0.23037781330885523f, 0,0,0,0},
  {-0.007800708325034148f, -0.0017677118642428036f, 0.04472490177066578f, 0.021060292512300564f,
   -0.07263752278646252f, -0.3379294217276218f, 0.787641141030194f, -0.4910559419267466f,
   -0.048311742585633f, 0.11799011114819057f, 0.0034907120842174702f, -0.015404109327027373f},
  {-0.08838834764831845f, -0.08838834764831845f, 0.7071067811865476f, -0.7071067811865476f,
    0.08838834764831845f, 0.08838834764831845f, 0,0,0,0,0,0},
};

__device__ __forceinline__ v2f sv(float c) { return v2f{c, c}; }

// O=8 outputs per thread. Coefficient kk valid while 2kk+2-L <= 7 -> KT=L/2+3.
template <int W, int KK>
__device__ __forceinline__ void step(const v2f (&xw)[28], v2f (&acc)[8],
                                     const v2f la, const v2f ld, const v2f gw) {
  constexpr int L = LW[W];
  if constexpr (KK < L / 2 + 3) {
    v2f lo = {0.f, 0.f}, hi = {0.f, 0.f};
#pragma unroll
    for (int m = 0; m < L; ++m) {
      const v2f xv = xw[2 * KK + 11 - m];
      if (DLf[W][m] != 0.0f) lo += sv(DLf[W][m]) * xv;
      if (DHf[W][m] != 0.0f) hi += sv(DHf[W][m]) * xv;
    }
    v2f cl, ch;
    cl.x = __builtin_amdgcn_fmed3f(lo.x, -la.x, la.x);
    cl.y = __builtin_amdgcn_fmed3f(lo.y, -la.y, la.y);
    ch.x = __builtin_amdgcn_fmed3f(hi.x, -ld.x, ld.x);
    ch.y = __builtin_amdgcn_fmed3f(hi.y, -ld.y, ld.y);
    const v2f loS = (lo - cl) * gw;
    const v2f hiS = (hi - ch) * gw;
#pragma unroll
    for (int m = 0; m < L; ++m) {
      const int j = 2 * KK + m + 2 - L;   // compile-time after unroll
      if (j >= 0 && j < 8) {
        if (RLf[W][m] != 0.0f) acc[j] += loS * sv(RLf[W][m]);
        if (RHf[W][m] != 0.0f) acc[j] += hiS * sv(RHf[W][m]);
      }
    }
  }
}

template <int KK>
__device__ __forceinline__ void sweep(const v2f (&xw)[28], v2f (&acc)[8],
                                      const v2f la, const v2f ld,
                                      const v2f gw0, const v2f gw1,
                                      const v2f gw2, const v2f gw3) {
  if constexpr (KK < 9) {   // max KT = sym6: 12/2+3 = 9
    step<0, KK>(xw, acc, la, ld, gw0);
    step<1, KK>(xw, acc, la, ld, gw1);
    step<2, KK>(xw, acc, la, ld, gw2);
    step<3, KK>(xw, acc, la, ld, gw3);
    if constexpr (KK < 4) {
      acc[2 * KK]     += xw[2 * KK + 10];   // residual y = x + sum w_i rec_i
      acc[2 * KK + 1] += xw[2 * KK + 11];
    }
    sweep<KK + 1>(xw, acc, la, ld, gw0, gw1, gw2, gw3);
  }
}

__device__ __forceinline__ void gload_lds16(const float* gsrc, float* ldst) {
  __builtin_amdgcn_global_load_lds(
      (const __attribute__((address_space(1))) void*)gsrc,
      (__attribute__((address_space(3))) void*)ldst, 16, 0, 0);
}

// 512-thread block over 64ch x 128pos tile: 8 positions per thread, 2 ch per
// thread. 37.9KB LDS -> 4 blocks/CU x 8 waves = 8 waves/SIMD max (vs R9's 4).
// Staging via global_load_lds unchanged.
__global__ __launch_bounds__(512) void wlm_k1(
    const float* __restrict__ x,
    const float* __restrict__ la_, const float* __restrict__ ld_,
    const float* __restrict__ lg_, const float* __restrict__ th_,
    const float* __restrict__ bl_, float* __restrict__ y) {
  __shared__ float xs[TILE_P][64];   // 37,888 B

  const int tid  = threadIdx.x;
  const int lane = tid & 63;
  const int wave = tid >> 6;         // 0..7
  const int s0 = blockIdx.x * SC;
  const int e0 = blockIdx.y * 64;
  const int b  = blockIdx.z;
  const size_t rowb = (size_t)b * T_SEQ;

  // ---- stage: 37 row-groups of 4 pos-rows across 8 waves ----
  {
    const int ch4  = (lane & 15) * 4;
#pragma unroll
    for (int it = 0; it < 5; ++it) {
      const int rg = wave + it * 8;
      if (rg < TILE_P / 4) {
        const int pos = rg * 4 + (lane >> 4);
        int g = s0 - 10 + pos;
        g = (g < 0) ? -g : g;
        g = (g >= T_SEQ) ? (2 * T_SEQ - 2 - g) : g;
        gload_lds16(&x[(rowb + g) * E_DIM + e0 + ch4], &xs[rg * 4][0]);
      }
    }
  }

  // ---- params: c = ch-pair (0..31), pg = position group (0..15) ----
  const int c  = tid & 31;
  const int pg = tid >> 5;
  const int e  = e0 + 2 * c;
  const v2f la = *reinterpret_cast<const v2f*>(&la_[e]);
  const v2f ld = *reinterpret_cast<const v2f*>(&ld_[e]);
  const v2f lg = *reinterpret_cast<const v2f*>(&lg_[e]);
  const v2f th = *reinterpret_cast<const v2f*>(&th_[e]);
  v2f g2;
  g2.x = (fmaxf(lg.x, 0.f) + log1pf(expf(-fabsf(lg.x))) + 1e-6f) * cosf(th.x);
  g2.y = (fmaxf(lg.y, 0.f) + log1pf(expf(-fabsf(lg.y))) + 1e-6f) * cosf(th.y);

  const float b0 = bl_[0], b1 = bl_[1], b2 = bl_[2], b3 = bl_[3];
  const float mx = fmaxf(fmaxf(b0, b1), fmaxf(b2, b3));
  const float w0 = expf(b0 - mx), w1 = expf(b1 - mx),
              w2 = expf(b2 - mx), w3 = expf(b3 - mx);
  const float wr = 1.f / (w0 + w1 + w2 + w3);
  const v2f gw0 = g2 * sv(w0 * wr), gw1 = g2 * sv(w1 * wr),
            gw2 = g2 * sv(w2 * wr), gw3 = g2 * sv(w3 * wr);

  __syncthreads();   // drains the global_load_lds queue

  // ---- window from LDS: x_ref[sA-10 .. sA+17], sA = s0 + pg*8 ----
  v2f xw[28];
#pragma unroll
  for (int i = 0; i < 28; ++i) {
    xw[i] = *reinterpret_cast<const v2f*>(&xs[pg * 8 + i][2 * c]);  // ds_read_b64
  }

  v2f acc[8];
#pragma unroll
  for (int j = 0; j < 8; ++j) acc[j] = v2f{0.f, 0.f};

  sweep<0>(xw, acc, la, ld, gw0, gw1, gw2, gw3);

  // ---- store (residual folded in during sweep) ----
  const int sA = s0 + pg * 8;
#pragma unroll
  for (int j = 0; j < 8; ++j) {
    *reinterpret_cast<v2f*>(&y[(rowb + sA + j) * E_DIM + e]) = acc[j];
  }
}

__global__ __launch_bounds__(256) void wlm_k2(float* __restrict__ y,
                                              const float* __restrict__ w,
                                              const float* __restrict__ bias) {
  const int token = blockIdx.x;
  const int tid = threadIdx.x;
  float* row = y + (size_t)token * E_DIM;

  float4 v = *reinterpret_cast<const float4*>(&row[tid * 4]);
  float s  = v.x + v.y + v.z + v.w;
  float sq = v.x * v.x + v.y * v.y + v.z * v.z + v.w * v.w;
#pragma unroll
  for (int off = 32; off; off >>= 1) {
    s  += __shfl_down(s, off);
    sq += __shfl_down(sq, off);
  }
  __shared__ float ps[4], pq[4], stat[2];
  const int wave = tid >> 6, lane = tid & 63;
  if (lane == 0) { ps[wave] = s; pq[wave] = sq; }
  __syncthreads();
  if (tid == 0) {
    const float S1 = ps[0] + ps[1] + ps[2] + ps[3];
    const float S2 = pq[0] + pq[1] + pq[2] + pq[3];
    const float mu = S1 * (1.f / E_DIM);
    const float var = S2 * (1.f / E_DIM) - mu * mu;
    stat[0] = mu;
    stat[1] = rsqrtf(var + 1e-5f);
  }
  __syncthreads();
  const float mu = stat[0], rstd = stat[1];
  const float4 wv = *reinterpret_cast<const float4*>(&w[tid * 4]);
  const float4 bv = *reinterpret_cast<const float4*>(&bias[tid * 4]);
  float4 o;
  o.x = (v.x - mu) * rstd * wv.x + bv.x;
  o.y = (v.y - mu) * rstd * wv.y + bv.y;
  o.z = (v.z - mu) * rstd * wv.z + bv.z;
  o.w = (v.w - mu) * rstd * wv.w + bv.w;
  *reinterpret_cast<float4*>(&row[tid * 4]) = o;
}

extern "C" void kernel_launch(void* const* d_in, const int* in_sizes, int n_in,
                              void* d_out, int out_size, void* d_ws, size_t ws_size,
                              hipStream_t stream) {
  const float* x   = (const float*)d_in[0];
  const float* la  = (const float*)d_in[1];
  const float* ldt = (const float*)d_in[2];
  const float* lg  = (const float*)d_in[3];
  const float* th  = (const float*)d_in[4];
  const float* bl  = (const float*)d_in[5];
  const float* lnw = (const float*)d_in[6];
  const float* lnb = (const float*)d_in[7];
  float* out = (float*)d_out;

  dim3 g1(T_SEQ / SC, E_DIM / 64, N_B);  // (32, 16, 8)
  wlm_k1<<<g1, 512, 0, stream>>>(x, la, ldt, lg, th, bl, out);
  wlm_k2<<<dim3(N_B * T_SEQ), 256, 0, stream>>>(out, lnw, lnb);
}

// Round 11
// 125.875 us; speedup vs baseline: 1.0078x; 1.0078x over previous
//
#include <hip/hip_runtime.h>
#include <cstdint>

#define T_SEQ 4096
#define E_DIM 1024
#define N_B   8
#define SC    128      // seq positions per block
#define TILE_P 148     // s0-10 .. s0+137 (37 groups of 4 rows)
typedef float v2f __attribute__((ext_vector_type(2)));

constexpr int LW[4] = {2, 8, 12, 6};

// dec_lo
constexpr float DLf[4][12] = {
  {0.7071067811865476f, 0.7071067811865476f, 0,0,0,0,0,0,0,0,0,0},
  {-0.010597401784997278f, 0.032883011666982945f, 0.030841381835986965f, -0.18703481171888114f,
   -0.02798376941698385f, 0.6308807679295904f, 0.7148465705525415f, 0.23037781330885523f, 0,0,0,0},
  {-0.007800708325034148f, 0.0017677118642428036f, 0.04472490177066578f, -0.021060292512300564f,
   -0.07263752278646252f, 0.3379294217276218f, 0.787641141030194f, 0.4910559419267466f,
   -0.048311742585633f, -0.11799011114819057f, 0.0034907120842174702f, 0.015404109327027373f},
  {-0.08838834764831845f, 0.08838834764831845f, 0.7071067811865476f, 0.7071067811865476f,
    0.08838834764831845f, -0.08838834764831845f, 0,0,0,0,0,0},
};
// dec_hi
constexpr float DHf[4][12] = {
  {-0.7071067811865476f, 0.7071067811865476f, 0,0,0,0,0,0,0,0,0,0},
  {-0.23037781330885523f, 0.7148465705525415f, -0.6308807679295904f, -0.02798376941698385f,
    0.18703481171888114f, 0.030841381835986965f, -0.032883011666982945f, -0.010597401784997278f, 0,0,0,0},
  {-0.015404109327027373f, 0.0034907120842174702f, 0.11799011114819057f, -0.048311742585633f,
   -0.4910559419267466f, 0.787641141030194f, -0.3379294217276218f, -0.07263752278646252f,
    0.021060292512300564f, 0.04472490177066578f, -0.0017677118642428036f, -0.007800708325034148f},
  {0,0,-0.7071067811865476f, 0.7071067811865476f, 0,0, 0,0,0,0,0,0},
};
// rec_lo
constexpr float RLf[4][12] = {
  {0.7071067811865476f, 0.7071067811865476f, 0,0,0,0,0,0,0,0,0,0},
  {0.23037781330885523f, 0.7148465705525415f, 0.6308807679295904f, -0.02798376941698385f,
   -0.18703481171888114f, 0.030841381835986965f, 0.032883011666982945f, -0.010597401784997278f, 0,0,0,0},
  {0.015404109327027373f, 0.0034907120842174702f, -0.11799011114819057f, -0.048311742585633f,
   0.4910559419267466f, 0.787641141030194f, 0.3379294217276218f, -0.07263752278646252f,
   -0.021060292512300564f, 0.04472490177066578f, 0.0017677118642428036f, -0.007800708325034148f},
  {0,0,0.7071067811865476f, 0.7071067811865476f, 0,0, 0,0,0,0,0,0},
};
// rec_hi
constexpr float RHf[4][12] = {
  {0.7071067811865476f, -0.7071067811865476f, 0,0,0,0,0,0,0,0,0,0},
  {-0.010597401784997278f, -0.032883011666982945f, 0.030841381835986965f, 0.18703481171888114f,
   -0.02798376941698385f, -0.6308807679295904f, 0.7148465705525415f, -0.23037781330885523f, 0,0,0,0},
  {-0.007800708325034148f, -0.0017677118642428036f, 0.04472490177066578f, 0.021060292512300564f,
   -0.07263752278646252f, -0.3379294217276218f, 0.787641141030194f, -0.4910559419267466f,
   -0.048311742585633f, 0.11799011114819057f, 0.0034907120842174702f, -0.015404109327027373f},
  {-0.08838834764831845f, -0.08838834764831845f, 0.7071067811865476f, -0.7071067811865476f,
    0.08838834764831845f, 0.08838834764831845f, 0,0,0,0,0,0},
};

__device__ __forceinline__ v2f sv(float c) { return v2f{c, c}; }

// O=8 outputs per thread. Coefficient kk valid while 2kk+2-L <= 7 -> KT=L/2+3.
template <int W, int KK>
__device__ __forceinline__ void step(const v2f (&xw)[28], v2f (&acc)[8],
                                     const v2f la, const v2f ld, const v2f gw) {
  constexpr int L = LW[W];
  if constexpr (KK < L / 2 + 3) {
    v2f lo = {0.f, 0.f}, hi = {0.f, 0.f};
#pragma unroll
    for (int m = 0; m < L; ++m) {
      const v2f xv = xw[2 * KK + 11 - m];
      if (DLf[W][m] != 0.0f) lo += sv(DLf[W][m]) * xv;
      if (DHf[W][m] != 0.0f) hi += sv(DHf[W][m]) * xv;
    }
    v2f cl, ch;
    cl.x = __builtin_amdgcn_fmed3f(lo.x, -la.x, la.x);
    cl.y = __builtin_amdgcn_fmed3f(lo.y, -la.y, la.y);
    ch.x = __builtin_amdgcn_fmed3f(hi.x, -ld.x, ld.x);
    ch.y = __builtin_amdgcn_fmed3f(hi.y, -ld.y, ld.y);
    const v2f loS = (lo - cl) * gw;
    const v2f hiS = (hi - ch) * gw;
#pragma unroll
    for (int m = 0; m < L; ++m) {
      const int j = 2 * KK + m + 2 - L;   // compile-time after unroll
      if (j >= 0 && j < 8) {
        if (RLf[W][m] != 0.0f) acc[j] += loS * sv(RLf[W][m]);
        if (RHf[W][m] != 0.0f) acc[j] += hiS * sv(RHf[W][m]);
      }
    }
  }
}

template <int KK>
__device__ __forceinline__ void sweep(const v2f (&xw)[28], v2f (&acc)[8],
                                      const v2f la, const v2f ld,
                                      const v2f gw0, const v2f gw1,
                                      const v2f gw2, const v2f gw3) {
  if constexpr (KK < 9) {   // max KT = sym6: 12/2+3 = 9
    step<0, KK>(xw, acc, la, ld, gw0);
    step<1, KK>(xw, acc, la, ld, gw1);
    step<2, KK>(xw, acc, la, ld, gw2);
    step<3, KK>(xw, acc, la, ld, gw3);
    if constexpr (KK < 4) {
      acc[2 * KK]     += xw[2 * KK + 10];   // residual y = x + sum w_i rec_i
      acc[2 * KK + 1] += xw[2 * KK + 11];
    }
    sweep<KK + 1>(xw, acc, la, ld, gw0, gw1, gw2, gw3);
  }
}

__device__ __forceinline__ void gload_lds16(const float* gsrc, float* ldst) {
  __builtin_amdgcn_global_load_lds(
      (const __attribute__((address_space(1))) void*)gsrc,
      (__attribute__((address_space(3))) void*)ldst, 16, 0, 0);
}

// 512-thread block over 64ch x 128pos tile: 8 positions per thread, 2 ch per
// thread. 37.9KB LDS -> 4 blocks/CU x 8 waves = 8 waves/SIMD max (vs R9's 4).
// Staging via global_load_lds unchanged.
__global__ __launch_bounds__(512) void wlm_k1(
    const float* __restrict__ x,
    const float* __restrict__ la_, const float* __restrict__ ld_,
    const float* __restrict__ lg_, const float* __restrict__ th_,
    const float* __restrict__ bl_, float* __restrict__ y) {
  __shared__ float xs[TILE_P][64];   // 37,888 B

  const int tid  = threadIdx.x;
  const int lane = tid & 63;
  const int wave = tid >> 6;         // 0..7
  const int s0 = blockIdx.x * SC;
  const int e0 = blockIdx.y * 64;
  const int b  = blockIdx.z;
  const size_t rowb = (size_t)b * T_SEQ;

  // ---- stage: 37 row-groups of 4 pos-rows across 8 waves ----
  {
    const int ch4  = (lane & 15) * 4;
#pragma unroll
    for (int it = 0; it < 5; ++it) {
      const int rg = wave + it * 8;
      if (rg < TILE_P / 4) {
        const int pos = rg * 4 + (lane >> 4);
        int g = s0 - 10 + pos;
        g = (g < 0) ? -g : g;
        g = (g >= T_SEQ) ? (2 * T_SEQ - 2 - g) : g;
        gload_lds16(&x[(rowb + g) * E_DIM + e0 + ch4], &xs[rg * 4][0]);
      }
    }
  }

  // ---- params: c = ch-pair (0..31), pg = position group (0..15) ----
  const int c  = tid & 31;
  const int pg = tid >> 5;
  const int e  = e0 + 2 * c;
  const v2f la = *reinterpret_cast<const v2f*>(&la_[e]);
  const v2f ld = *reinterpret_cast<const v2f*>(&ld_[e]);
  const v2f lg = *reinterpret_cast<const v2f*>(&lg_[e]);
  const v2f th = *reinterpret_cast<const v2f*>(&th_[e]);
  v2f g2;
  g2.x = (fmaxf(lg.x, 0.f) + log1pf(expf(-fabsf(lg.x))) + 1e-6f) * cosf(th.x);
  g2.y = (fmaxf(lg.y, 0.f) + log1pf(expf(-fabsf(lg.y))) + 1e-6f) * cosf(th.y);

  const float b0 = bl_[0], b1 = bl_[1], b2 = bl_[2], b3 = bl_[3];
  const float mx = fmaxf(fmaxf(b0, b1), fmaxf(b2, b3));
  const float w0 = expf(b0 - mx), w1 = expf(b1 - mx),
              w2 = expf(b2 - mx), w3 = expf(b3 - mx);
  const float wr = 1.f / (w0 + w1 + w2 + w3);
  const v2f gw0 = g2 * sv(w0 * wr), gw1 = g2 * sv(w1 * wr),
            gw2 = g2 * sv(w2 * wr), gw3 = g2 * sv(w3 * wr);

  __syncthreads();   // drains the global_load_lds queue

  // ---- window from LDS: x_ref[sA-10 .. sA+17], sA = s0 + pg*8 ----
  v2f xw[28];
#pragma unroll
  for (int i = 0; i < 28; ++i) {
    xw[i] = *reinterpret_cast<const v2f*>(&xs[pg * 8 + i][2 * c]);  // ds_read_b64
  }

  v2f acc[8];
#pragma unroll
  for (int j = 0; j < 8; ++j) acc[j] = v2f{0.f, 0.f};

  sweep<0>(xw, acc, la, ld, gw0, gw1, gw2, gw3);

  // ---- store (residual folded in during sweep) ----
  const int sA = s0 + pg * 8;
#pragma unroll
  for (int j = 0; j < 8; ++j) {
    *reinterpret_cast<v2f*>(&y[(rowb + sA + j) * E_DIM + e]) = acc[j];
  }
}

__global__ __launch_bounds__(256) void wlm_k2(float* __restrict__ y,
                                              const float* __restrict__ w,
                                              const float* __restrict__ bias) {
  const int token = blockIdx.x;
  const int tid = threadIdx.x;
  float* row = y + (size_t)token * E_DIM;

  float4 v = *reinterpret_cast<const float4*>(&row[tid * 4]);
  float s  = v.x + v.y + v.z + v.w;
  float sq = v.x * v.x + v.y * v.y + v.z * v.z + v.w * v.w;
#pragma unroll
  for (int off = 32; off; off >>= 1) {
    s  += __shfl_down(s, off);
    sq += __shfl_down(sq, off);
  }
  __shared__ float ps[4], pq[4], stat[2];
  const int wave = tid >> 6, lane = tid & 63;
  if (lane == 0) { ps[wave] = s; pq[wave] = sq; }
  __syncthreads();
  if (tid == 0) {
    const float S1 = ps[0] + ps[1] + ps[2] + ps[3];
    const float S2 = pq[0] + pq[1] + pq[2] + pq[3];
    const float mu = S1 * (1.f / E_DIM);
    const float var = S2 * (1.f / E_DIM) - mu * mu;
    stat[0] = mu;
    stat[1] = rsqrtf(var + 1e-5f);
  }
  __syncthreads();
  const float mu = stat[0], rstd = stat[1];
  const float4 wv = *reinterpret_cast<const float4*>(&w[tid * 4]);
  const float4 bv = *reinterpret_cast<const float4*>(&bias[tid * 4]);
  float4 o;
  o.x = (v.x - mu) * rstd * wv.x + bv.x;
  o.y = (v.y - mu) * rstd * wv.y + bv.y;
  o.z = (v.z - mu) * rstd * wv.z + bv.z;
  o.w = (v.w - mu) * rstd * wv.w + bv.w;
  *reinterpret_cast<float4*>(&row[tid * 4]) = o;
}

extern "C" void kernel_launch(void* const* d_in, const int* in_sizes, int n_in,
                              void* d_out, int out_size, void* d_ws, size_t ws_size,
                              hipStream_t stream) {
  const float* x   = (const float*)d_in[0];
  const float* la  = (const float*)d_in[1];
  const float* ldt = (const float*)d_in[2];
  const float* lg  = (const float*)d_in[3];
  const float* th  = (const float*)d_in[4];
  const float* bl  = (const float*)d_in[5];
  const float* lnw = (const float*)d_in[6];
  const float* lnb = (const float*)d_in[7];
  float* out = (float*)d_out;

  dim3 g1(T_SEQ / SC, E_DIM / 64, N_B);  // (32, 16, 8)
  wlm_k1<<<g1, 512, 0, stream>>>(x, la, ldt, lg, th, bl, out);
  wlm_k2<<<dim3(N_B * T_SEQ), 256, 0, stream>>>(out, lnw, lnb);
}

// Round 12
// 113.794 us; speedup vs baseline: 1.1148x; 1.1062x over previous
//
#include <hip/hip_runtime.h>
#include <cstdint>

#define T_SEQ 4096
#define E_DIM 1024
#define N_B   8
#define SC    64       // seq positions per block
typedef float v2f __attribute__((ext_vector_type(2)));

constexpr int LW[4] = {2, 8, 12, 6};

// dec_lo
constexpr float DLf[4][12] = {
  {0.7071067811865476f, 0.7071067811865476f, 0,0,0,0,0,0,0,0,0,0},
  {-0.010597401784997278f, 0.032883011666982945f, 0.030841381835986965f, -0.18703481171888114f,
   -0.02798376941698385f, 0.6308807679295904f, 0.7148465705525415f, 0.23037781330885523f, 0,0,0,0},
  {-0.007800708325034148f, 0.0017677118642428036f, 0.04472490177066578f, -0.021060292512300564f,
   -0.07263752278646252f, 0.3379294217276218f, 0.787641141030194f, 0.4910559419267466f,
   -0.048311742585633f, -0.11799011114819057f, 0.0034907120842174702f, 0.015404109327027373f},
  {-0.08838834764831845f, 0.08838834764831845f, 0.7071067811865476f, 0.7071067811865476f,
    0.08838834764831845f, -0.08838834764831845f, 0,0,0,0,0,0},
};
// dec_hi
constexpr float DHf[4][12] = {
  {-0.7071067811865476f, 0.7071067811865476f, 0,0,0,0,0,0,0,0,0,0},
  {-0.23037781330885523f, 0.7148465705525415f, -0.6308807679295904f, -0.02798376941698385f,
    0.18703481171888114f, 0.030841381835986965f, -0.032883011666982945f, -0.010597401784997278f, 0,0,0,0},
  {-0.015404109327027373f, 0.0034907120842174702f, 0.11799011114819057f, -0.048311742585633f,
   -0.4910559419267466f, 0.787641141030194f, -0.3379294217276218f, -0.07263752278646252f,
    0.021060292512300564f, 0.04472490177066578f, -0.0017677118642428036f, -0.007800708325034148f},
  {0,0,-0.7071067811865476f, 0.7071067811865476f, 0,0, 0,0,0,0,0,0},
};
// rec_lo
constexpr float RLf[4][12] = {
  {0.7071067811865476f, 0.7071067811865476f, 0,0,0,0,0,0,0,0,0,0},
  {0.23037781330885523f, 0.7148465705525415f, 0.6308807679295904f, -0.02798376941698385f,
   -0.18703481171888114f, 0.030841381835986965f, 0.032883011666982945f, -0.010597401784997278f, 0,0,0,0},
  {0.015404109327027373f, 0.0034907120842174702f, -0.11799011114819057f, -0.048311742585633f,
   0.4910559419267466f, 0.787641141030194f, 0.3379294217276218f, -0.07263752278646252f,
   -0.021060292512300564f, 0.04472490177066578f, 0.0017677118642428036f, -0.007800708325034148f},
  {0,0,0.7071067811865476f, 0.7071067811865476f, 0,0, 0,0,0,0,0,0},
};
// rec_hi
constexpr float RHf[4][12] = {
  {0.7071067811865476f, -0.7071067811865476f, 0,0,0,0,0,0,0,0,0,0},
  {-0.010597401784997278f, -0.032883011666982945f, 0.030841381835986965f, 0.18703481171888114f,
   -0.02798376941698385f, -0.6308807679295904f, 0.7148465705525415f, -0.23037781330885523f, 0,0,0,0},
  {-0.007800708325034148f, -0.0017677118642428036f, 0.04472490177066578f, 0.021060292512300564f,
   -0.07263752278646252f, -0.3379294217276218f, 0.787641141030194f, -0.4910559419267466f,
   -0.048311742585633f, 0.11799011114819057f, 0.0034907120842174702f, -0.015404109327027373f},
  {-0.08838834764831845f, -0.08838834764831845f, 0.7071067811865476f, -0.7071067811865476f,
    0.08838834764831845f, 0.08838834764831845f, 0,0,0,0,0,0},
};

__device__ __forceinline__ v2f sv(float c) { return v2f{c, c}; }

template <int W, int KK>
__device__ __forceinline__ void step(const v2f (&xw)[36], v2f (&acc)[16],
                                     const v2f la, const v2f ld, const v2f gw) {
  constexpr int L = LW[W];
  if constexpr (KK < L / 2 + 7) {
    v2f lo = {0.f, 0.f}, hi = {0.f, 0.f};
#pragma unroll
    for (int m = 0; m < L; ++m) {
      const v2f xv = xw[2 * KK + 11 - m];
      if (DLf[W][m] != 0.0f) lo += sv(DLf[W][m]) * xv;
      if (DHf[W][m] != 0.0f) hi += sv(DHf[W][m]) * xv;
    }
    v2f cl, ch;
    cl.x = __builtin_amdgcn_fmed3f(lo.x, -la.x, la.x);
    cl.y = __builtin_amdgcn_fmed3f(lo.y, -la.y, la.y);
    ch.x = __builtin_amdgcn_fmed3f(hi.x, -ld.x, ld.x);
    ch.y = __builtin_amdgcn_fmed3f(hi.y, -ld.y, ld.y);
    const v2f loS = (lo - cl) * gw;
    const v2f hiS = (hi - ch) * gw;
#pragma unroll
    for (int m = 0; m < L; ++m) {
      const int j = 2 * KK + m + 2 - L;   // compile-time after unroll
      if (j >= 0 && j < 16) {
        if (RLf[W][m] != 0.0f) acc[j] += loS * sv(RLf[W][m]);
        if (RHf[W][m] != 0.0f) acc[j] += hiS * sv(RHf[W][m]);
      }
    }
  }
}

template <int KK>
__device__ __forceinline__ void sweep(const v2f (&xw)[36], v2f (&acc)[16],
                                      const v2f la, const v2f ld,
                                      const v2f gw0, const v2f gw1,
                                      const v2f gw2, const v2f gw3) {
  if constexpr (KK < 13) {
    step<0, KK>(xw, acc, la, ld, gw0);
    step<1, KK>(xw, acc, la, ld, gw1);
    step<2, KK>(xw, acc, la, ld, gw2);
    step<3, KK>(xw, acc, la, ld, gw3);
    if constexpr (KK < 8) {
      acc[2 * KK]     += xw[2 * KK + 10];   // residual y = x + sum w_i rec_i
      acc[2 * KK + 1] += xw[2 * KK + 11];
    }
    sweep<KK + 1>(xw, acc, la, ld, gw0, gw1, gw2, gw3);
  }
}

// No LDS; channel pair (e, e+1) per thread, 16 positions per thread.
// waves_per_eu(3,4) raises the VGPR budget to ~170 (R6: +17%); the asm pins
// below then FORCE the 36 window loads to materialize up-front instead of
// being sunk just-in-time into the sweep (R1-R11: VGPR 52-72, ~60% stall).
__global__ __launch_bounds__(256)
__attribute__((amdgpu_waves_per_eu(3, 4)))
void wlm_k1(
    const float* __restrict__ x,
    const float* __restrict__ la_, const float* __restrict__ ld_,
    const float* __restrict__ lg_, const float* __restrict__ th_,
    const float* __restrict__ bl_, float* __restrict__ y) {
  const int tid  = threadIdx.x;
  const int lane = tid & 63;
  const int wave = tid >> 6;
  const int s0 = blockIdx.x * SC;
  const int e0 = blockIdx.y * 128;
  const int b  = blockIdx.z;
  const int e  = e0 + 2 * lane;
  const int sA = s0 + wave * 16;

  // ---- window: x_ref[sA-10 .. sA+25] for channel pair (e, e+1) ----
  const size_t rowb = (size_t)b * T_SEQ;
  v2f xw[36];
  if (sA >= 10 && sA + 26 <= T_SEQ) {
    const float* p = &x[(rowb + sA - 10) * E_DIM + e];
#pragma unroll
    for (int i = 0; i < 36; ++i) {
      xw[i] = *reinterpret_cast<const v2f*>(p + (size_t)i * E_DIM);
    }
  } else {
#pragma unroll
    for (int i = 0; i < 36; ++i) {
      int g = sA - 10 + i;
      g = (g < 0) ? -g : g;
      g = (g >= T_SEQ) ? (2 * T_SEQ - 2 - g) : g;
      xw[i] = *reinterpret_cast<const v2f*>(&x[(rowb + g) * E_DIM + e]);
    }
  }
  // Pin every window value into VGPRs NOW (budget exists this time), and
  // forbid the scheduler from sinking the loads past this point.
#pragma unroll
  for (int i = 0; i < 36; ++i) {
    asm volatile("" : "+v"(xw[i].x), "+v"(xw[i].y));
  }
  __builtin_amdgcn_sched_barrier(0);

  // ---- per-channel-pair params ----
  const v2f la = *reinterpret_cast<const v2f*>(&la_[e]);
  const v2f ld = *reinterpret_cast<const v2f*>(&ld_[e]);
  const v2f lg = *reinterpret_cast<const v2f*>(&lg_[e]);
  const v2f th = *reinterpret_cast<const v2f*>(&th_[e]);
  v2f g2;
  g2.x = (fmaxf(lg.x, 0.f) + log1pf(expf(-fabsf(lg.x))) + 1e-6f) * cosf(th.x);
  g2.y = (fmaxf(lg.y, 0.f) + log1pf(expf(-fabsf(lg.y))) + 1e-6f) * cosf(th.y);

  const float b0 = bl_[0], b1 = bl_[1], b2 = bl_[2], b3 = bl_[3];
  const float mx = fmaxf(fmaxf(b0, b1), fmaxf(b2, b3));
  const float w0 = expf(b0 - mx), w1 = expf(b1 - mx),
              w2 = expf(b2 - mx), w3 = expf(b3 - mx);
  const float wr = 1.f / (w0 + w1 + w2 + w3);
  const v2f gw0 = g2 * sv(w0 * wr), gw1 = g2 * sv(w1 * wr),
            gw2 = g2 * sv(w2 * wr), gw3 = g2 * sv(w3 * wr);

  v2f acc[16];
#pragma unroll
  for (int j = 0; j < 16; ++j) acc[j] = v2f{0.f, 0.f};

  sweep<0>(xw, acc, la, ld, gw0, gw1, gw2, gw3);

  // ---- store (residual folded in during the sweep) ----
#pragma unroll
  for (int j = 0; j < 16; ++j) {
    *reinterpret_cast<v2f*>(&y[(rowb + sA + j) * E_DIM + e]) = acc[j];
  }
}

__global__ __launch_bounds__(256) void wlm_k2(float* __restrict__ y,
                                              const float* __restrict__ w,
                                              const float* __restrict__ bias) {
  const int token = blockIdx.x;
  const int tid = threadIdx.x;
  float* row = y + (size_t)token * E_DIM;

  float4 v = *reinterpret_cast<const float4*>(&row[tid * 4]);
  float s  = v.x + v.y + v.z + v.w;
  float sq = v.x * v.x + v.y * v.y + v.z * v.z + v.w * v.w;
#pragma unroll
  for (int off = 32; off; off >>= 1) {
    s  += __shfl_down(s, off);
    sq += __shfl_down(sq, off);
  }
  __shared__ float ps[4], pq[4], stat[2];
  const int wave = tid >> 6, lane = tid & 63;
  if (lane == 0) { ps[wave] = s; pq[wave] = sq; }
  __syncthreads();
  if (tid == 0) {
    const float S1 = ps[0] + ps[1] + ps[2] + ps[3];
    const float S2 = pq[0] + pq[1] + pq[2] + pq[3];
    const float mu = S1 * (1.f / E_DIM);
    const float var = S2 * (1.f / E_DIM) - mu * mu;
    stat[0] = mu;
    stat[1] = rsqrtf(var + 1e-5f);
  }
  __syncthreads();
  const float mu = stat[0], rstd = stat[1];
  const float4 wv = *reinterpret_cast<const float4*>(&w[tid * 4]);
  const float4 bv = *reinterpret_cast<const float4*>(&bias[tid * 4]);
  float4 o;
  o.x = (v.x - mu) * rstd * wv.x + bv.x;
  o.y = (v.y - mu) * rstd * wv.y + bv.y;
  o.z = (v.z - mu) * rstd * wv.z + bv.z;
  o.w = (v.w - mu) * rstd * wv.w + bv.w;
  *reinterpret_cast<float4*>(&row[tid * 4]) = o;
}

extern "C" void kernel_launch(void* const* d_in, const int* in_sizes, int n_in,
                              void* d_out, int out_size, void* d_ws, size_t ws_size,
                              hipStream_t stream) {
  const float* x   = (const float*)d_in[0];
  const float* la  = (const float*)d_in[1];
  const float* ldt = (const float*)d_in[2];
  const float* lg  = (const float*)d_in[3];
  const float* th  = (const float*)d_in[4];
  const float* bl  = (const float*)d_in[5];
  const float* lnw = (const float*)d_in[6];
  const float* lnb = (const float*)d_in[7];
  float* out = (float*)d_out;

  dim3 g1(T_SEQ / SC, E_DIM / 128, N_B);  // (64, 8, 8)
  wlm_k1<<<g1, 256, 0, stream>>>(x, la, ldt, lg, th, bl, out);
  wlm_k2<<<dim3(N_B * T_SEQ), 256, 0, stream>>>(out, lnw, lnb);
}